// Round 4
// baseline (3928.388 us; speedup 1.0000x reference)
//
#include <hip/hip_runtime.h>

#define VOCAB 28996
#define BB 32
#define SS 512
#define DD 768
#define NCLS 9
#define ROWS (BB*SS)     // 16384
#define IN2 (2*DD)       // 1536
#define G4 (4*DD)        // 3072
#define NB2 (2*G4)       // 6144

typedef __attribute__((ext_vector_type(8))) short short8;
typedef __attribute__((ext_vector_type(4))) float floatx4;

__device__ __forceinline__ float bf2f(unsigned short u){
  union { unsigned int i; float f; } v; v.i = ((unsigned int)u) << 16; return v.f;
}
__device__ __forceinline__ unsigned short f2bf(float f){
  union { float f; unsigned int i; } v; v.f = f;
  unsigned int r = v.i + 0x7FFFu + ((v.i >> 16) & 1u);
  return (unsigned short)(r >> 16);
}
__device__ __forceinline__ float sigf(float x){ return 1.0f / (1.0f + __expf(-x)); }

__device__ __forceinline__ void gl_lds16(const unsigned short* g, unsigned short* l){
  __builtin_amdgcn_global_load_lds((__attribute__((address_space(1))) void*)(g),
                                   (__attribute__((address_space(3))) void*)(l), 16, 0, 0);
}

// ---- manual grid barrier: sense-reversing counter, device-scope atomics ----
// bar[0] = arrival counter, bar[1] = generation. Safe for co-resident grids
// (grid <= 192 blocks, 16KB LDS, 4 waves -> always co-resident on 256 CUs).
__device__ __forceinline__ void grid_bar(unsigned* bar, int nb)
{
  __threadfence();          // publish this block's global stores (agent scope)
  __syncthreads();
  if (threadIdx.x == 0) {
    unsigned g = __hip_atomic_load(bar + 1, __ATOMIC_RELAXED, __HIP_MEMORY_SCOPE_AGENT);
    unsigned a = __hip_atomic_fetch_add(bar, 1u, __ATOMIC_ACQ_REL, __HIP_MEMORY_SCOPE_AGENT);
    if (a == (unsigned)(nb - 1)) {
      __hip_atomic_store(bar, 0u, __ATOMIC_RELAXED, __HIP_MEMORY_SCOPE_AGENT);
      __hip_atomic_store(bar + 1, g + 1u, __ATOMIC_RELEASE, __HIP_MEMORY_SCOPE_AGENT);
    } else {
      unsigned cur;
      do {
        __builtin_amdgcn_s_sleep(2);
        cur = __hip_atomic_load(bar + 1, __ATOMIC_ACQUIRE, __HIP_MEMORY_SCOPE_AGENT);
      } while (cur == g);
    }
  }
  __syncthreads();
  __threadfence();          // invalidate stale cached lines before next reads
}

// ---------------- segment mean ----------------
__global__ void seg_scatter(const int* __restrict__ ids, const float* __restrict__ hidden,
                            float* __restrict__ sums, float* __restrict__ counts)
{
  int r = blockIdx.x;
  int id = ids[r];
  const float* h = hidden + (long)r * DD;
  float* s = sums + (long)id * DD;
  for (int d = threadIdx.x; d < DD; d += 256)
    atomicAdd(&s[d], h[d]);
  if (threadIdx.x == 0) atomicAdd(&counts[id], 1.0f);
}

__global__ void build_x(const int* __restrict__ ids, const float* __restrict__ hidden,
                        const float* __restrict__ sums, const float* __restrict__ counts,
                        unsigned short* __restrict__ x)
{
  int r = blockIdx.x;
  int id = ids[r];
  float inv = 1.0f / fmaxf(counts[id], 1.0f);
  const float* h = hidden + (long)r * DD;
  const float* s = sums + (long)id * DD;
  unsigned short* xr = x + (long)r * IN2;
  for (int d = threadIdx.x; d < DD; d += 256) {
    xr[d]      = f2bf(h[d]);
    xr[DD + d] = f2bf(s[d] * inv);
  }
}

// -------- weight conversion with gate-interleave permutation: row' = u*4+g <- row g*768+u --------
__global__ void conv_w_perm(const float* __restrict__ w, unsigned short* __restrict__ o, int K)
{
  long i = (long)blockIdx.x * 256 + threadIdx.x;   // over 3072*K
  if (i >= (long)G4 * K) return;
  int row = (int)(i / K); int k = (int)(i - (long)row * K);
  int u = row >> 2, g = row & 3;
  o[i] = f2bf(w[((long)(g * DD + u)) * K + k]);
}

__global__ void conv_bias_perm(const float* __restrict__ bif, const float* __restrict__ bhf,
                               const float* __restrict__ bib, const float* __restrict__ bhb,
                               float* __restrict__ o)
{
  int n = blockIdx.x * 256 + threadIdx.x;
  if (n >= NB2) return;
  int d = n / G4, rr = n - d * G4, u = rr >> 2, g = rr & 3;
  int s = g * DD + u;
  o[n] = d ? (bib[s] + bhb[s]) : (bif[s] + bhf[s]);
}

// ---------------- GEMM: C[m,n] = sum_k A[m,k]*B[n,k] + bias[n], bf16 out ----------------
__global__ __launch_bounds__(256, 2)
void gemm_bt(const unsigned short* __restrict__ A, int lda,
             const unsigned short* __restrict__ B, int ldb,
             unsigned short* __restrict__ C, int ldc,
             const float* __restrict__ bias, int K)
{
  __shared__ unsigned short lA[128 * 32];
  __shared__ unsigned short lB[128 * 32];
  const int t = threadIdx.x;
  const int lane = t & 63;
  const int wv = t >> 6;
  const int wm = wv >> 1, wn = wv & 1;
  const int l15 = lane & 15, q = lane >> 4;
  const long m0 = (long)blockIdx.y * 128;
  const long n0 = (long)blockIdx.x * 128;
  const int rowS = t >> 2;
  const int kc = (t & 3) * 8;
  const unsigned short* gA = A + (m0 + rowS) * lda + kc;
  const unsigned short* gB = B + (n0 + rowS) * ldb + kc;
  unsigned short* dA0 = lA + (wv << 9);
  unsigned short* dA1 = lA + 2048 + (wv << 9);
  unsigned short* dB0 = lB + (wv << 9);
  unsigned short* dB1 = lB + 2048 + (wv << 9);

  floatx4 acc[4][4];
  #pragma unroll
  for (int i = 0; i < 4; i++)
    #pragma unroll
    for (int j = 0; j < 4; j++)
      acc[i][j] = (floatx4){0.f, 0.f, 0.f, 0.f};

  const long a64 = (long)64 * lda;
  const long b64 = (long)64 * ldb;
  for (int kt = 0; kt < K; kt += 32) {
    gl_lds16(gA + kt,       dA0);
    gl_lds16(gA + a64 + kt, dA1);
    gl_lds16(gB + kt,       dB0);
    gl_lds16(gB + b64 + kt, dB1);
    __syncthreads();
    short8 af[4], bfr[4];
    #pragma unroll
    for (int i = 0; i < 4; i++)
      af[i] = *(const short8*)(lA + (wm * 64 + i * 16 + l15) * 32 + q * 8);
    #pragma unroll
    for (int j = 0; j < 4; j++)
      bfr[j] = *(const short8*)(lB + (wn * 64 + j * 16 + l15) * 32 + q * 8);
    #pragma unroll
    for (int i = 0; i < 4; i++)
      #pragma unroll
      for (int j = 0; j < 4; j++)
        acc[i][j] = __builtin_amdgcn_mfma_f32_16x16x32_bf16(af[i], bfr[j], acc[i][j], 0, 0, 0);
    __syncthreads();
  }

  #pragma unroll
  for (int i = 0; i < 4; i++) {
    #pragma unroll
    for (int j = 0; j < 4; j++) {
      const long mg = m0 + wm * 64 + i * 16 + q * 4;
      const long ng = n0 + wn * 64 + j * 16 + l15;
      const float bb = bias[ng];
      #pragma unroll
      for (int r = 0; r < 4; r++)
        C[(mg + r) * ldc + ng] = f2bf(acc[i][j][r] + bb);
    }
  }
}

// ---------------- persistent bidirectional LSTM recurrence ----------------
// grid = ndir*96 blocks: per dir, 4 m-tiles (512 rows) x 24 n-tiles (3072 permuted gate-cols).
// Weights gate-interleaved (col = u*4+g): the 4 gates of unit u sit in 4 adjacent lanes.
// c stays in registers across all 32 steps; h ping-pongs via hbuf, one manual grid barrier/step.
__global__ __launch_bounds__(256, 1)
void lstm_persist(const unsigned short* __restrict__ xg, int ldxg,
                  const unsigned short* __restrict__ whh,   // [2][3072][768] permuted, global dir
                  unsigned short* __restrict__ hbuf,        // [2][ndir][512][768]
                  unsigned short* __restrict__ outc,        // [16384][1536]
                  unsigned* bar, int nblocks,
                  int dir0, int ndir)
{
  __shared__ unsigned short lA[128 * 32];
  __shared__ unsigned short lB[128 * 32];
  const int bid = blockIdx.x;
  const int ld = bid / 96;
  const int rr = bid - ld * 96;
  const int mt = rr / 24, nt = rr - (rr / 24) * 24;
  const int dir = dir0 + ld;
  const int t0 = threadIdx.x;
  const int lane = t0 & 63;
  const int wv = t0 >> 6;
  const int wm = wv >> 1, wn = wv & 1;
  const int l15 = lane & 15, q = lane >> 4;
  const int m0 = mt * 128, n0 = nt * 128;
  const int rowS = t0 >> 2;
  const int kc = (t0 & 3) * 8;
  const int baseLane = lane & ~3;

  const unsigned short* Bp = whh + (long)dir * G4 * DD + ((long)(n0 + rowS)) * DD + kc;
  unsigned short* dA0 = lA + (wv << 9);
  unsigned short* dA1 = lA + 2048 + (wv << 9);
  unsigned short* dB0 = lB + (wv << 9);
  unsigned short* dB1 = lB + 2048 + (wv << 9);
  const long s64 = (long)64 * DD;

  float c_reg[4][4][4];
  #pragma unroll
  for (int i = 0; i < 4; i++)
    #pragma unroll
    for (int j = 0; j < 4; j++)
      #pragma unroll
      for (int r = 0; r < 4; r++)
        c_reg[i][j][r] = 0.f;

  for (int s = 0; s < BB; s++) {
    const int t = dir ? (BB - 1 - s) : s;
    const unsigned short* Ap = hbuf + (((long)(s & 1)) * ndir + ld) * ((long)SS * DD)
                                    + ((long)(m0 + rowS)) * DD + kc;
    unsigned short* hw = hbuf + (((long)((s + 1) & 1)) * ndir + ld) * ((long)SS * DD);

    floatx4 acc[4][4];
    #pragma unroll
    for (int i = 0; i < 4; i++)
      #pragma unroll
      for (int j = 0; j < 4; j++)
        acc[i][j] = (floatx4){0.f, 0.f, 0.f, 0.f};

    for (int kt = 0; kt < DD; kt += 32) {
      gl_lds16(Ap + kt,       dA0);
      gl_lds16(Ap + s64 + kt, dA1);
      gl_lds16(Bp + kt,       dB0);
      gl_lds16(Bp + s64 + kt, dB1);
      __syncthreads();
      short8 af[4], bfr[4];
      #pragma unroll
      for (int i = 0; i < 4; i++)
        af[i] = *(const short8*)(lA + (wm * 64 + i * 16 + l15) * 32 + q * 8);
      #pragma unroll
      for (int j = 0; j < 4; j++)
        bfr[j] = *(const short8*)(lB + (wn * 64 + j * 16 + l15) * 32 + q * 8);
      #pragma unroll
      for (int i = 0; i < 4; i++)
        #pragma unroll
        for (int j = 0; j < 4; j++)
          acc[i][j] = __builtin_amdgcn_mfma_f32_16x16x32_bf16(af[i], bfr[j], acc[i][j], 0, 0, 0);
      __syncthreads();
    }

    // fused gate epilogue
    const unsigned short* xgp = xg + ((long)t * SS) * ldxg + (long)ld * G4;
    #pragma unroll
    for (int i = 0; i < 4; i++) {
      #pragma unroll
      for (int j = 0; j < 4; j++) {
        const int mg = m0 + wm * 64 + i * 16 + q * 4;
        const int ng = n0 + wn * 64 + j * 16 + l15;
        const int u  = ng >> 2;
        #pragma unroll
        for (int r = 0; r < 4; r++) {
          float v = acc[i][j][r] + bf2f(xgp[((long)(mg + r)) * ldxg + ng]);
          float gi = __shfl(v, baseLane + 0, 64);
          float gf = __shfl(v, baseLane + 1, 64);
          float gg = __shfl(v, baseLane + 2, 64);
          float go = __shfl(v, baseLane + 3, 64);
          float c = sigf(gf) * c_reg[i][j][r] + sigf(gi) * tanhf(gg);
          float h = sigf(go) * tanhf(c);
          c_reg[i][j][r] = c;
          if ((l15 & 3) == 0) {
            unsigned short hb = f2bf(h);
            hw[((long)(mg + r)) * DD + u] = hb;
            outc[((long)(t * SS + mg + r)) * IN2 + dir * DD + u] = hb;
          }
        }
      }
    }
    if (s < BB - 1) grid_bar(bar, nblocks);
  }
}

// ---------------- final linear [16384,1536](bf16) x [9,1536]^T ----------------
__global__ void final_linear(const unsigned short* __restrict__ xin, const float* __restrict__ w,
                             const float* __restrict__ b, float* __restrict__ out)
{
  __shared__ float red[NCLS * 256];
  int row = blockIdx.x;
  const unsigned short* x = xin + (long)row * IN2;
  float p[NCLS];
  #pragma unroll
  for (int c = 0; c < NCLS; c++) p[c] = 0.f;
  for (int k = threadIdx.x; k < IN2; k += 256) {
    float xv = bf2f(x[k]);
    #pragma unroll
    for (int c = 0; c < NCLS; c++) p[c] += xv * w[c * IN2 + k];
  }
  #pragma unroll
  for (int c = 0; c < NCLS; c++) red[c * 256 + threadIdx.x] = p[c];
  __syncthreads();
  for (int s = 128; s > 0; s >>= 1) {
    if (threadIdx.x < s) {
      #pragma unroll
      for (int c = 0; c < NCLS; c++)
        red[c * 256 + threadIdx.x] += red[c * 256 + threadIdx.x + s];
    }
    __syncthreads();
  }
  if (threadIdx.x < NCLS)
    out[(long)row * NCLS + threadIdx.x] = red[threadIdx.x * 256] + b[threadIdx.x];
}

extern "C" void kernel_launch(void* const* d_in, const int* in_sizes, int n_in,
                              void* d_out, int out_size, void* d_ws, size_t ws_size,
                              hipStream_t stream)
{
  const int*   batch  = (const int*)d_in[0];
  const float* hidden = (const float*)d_in[1];
  const float* w_ih_f = (const float*)d_in[2];
  const float* w_hh_f = (const float*)d_in[3];
  const float* b_ih_f = (const float*)d_in[4];
  const float* b_hh_f = (const float*)d_in[5];
  const float* w_ih_b = (const float*)d_in[6];
  const float* w_hh_b = (const float*)d_in[7];
  const float* b_ih_b = (const float*)d_in[8];
  const float* b_hh_b = (const float*)d_in[9];
  const float* lin_w  = (const float*)d_in[10];
  const float* lin_b  = (const float*)d_in[11];
  float* out = (float*)d_out;

  char* ws = (char*)d_ws;
  size_t off = 0;
  auto alloc = [&](size_t bytes) -> char* {
    char* p = ws + off;
    off += (bytes + 255) & ~(size_t)255;
    return p;
  };

  const size_t SZ_XG_A = (size_t)ROWS * NB2 * 2;      // 201.3 MB
  const size_t SZ_XG_B = (size_t)ROWS * G4  * 2;      // 100.7 MB
  const size_t SZ_XBF  = (size_t)ROWS * IN2 * 2;      //  50.3 MB
  const size_t SZ_W    = (size_t)G4 * IN2 * 2;        //   9.4 MB (== 2*G4*DD*2)
  const size_t SZ_BIAS = (size_t)NB2 * 4;
  const size_t SZ_HBUF = (size_t)2 * 2 * SS * DD * 2; //   3.1 MB
  const size_t SZ_BAR  = 256;
  const size_t SZ_SUMS = (size_t)VOCAB * DD * 4 + (size_t)VOCAB * 4;

  // combined layout: xg(both dirs) + xbf/outc + shared w buffer + bias + hbuf + bar  ~= 264.3 MB
  const size_t NEED_C = SZ_XG_A + SZ_XBF + SZ_W + SZ_BIAS + SZ_HBUF + SZ_BAR + 8 * 256;
  const bool combined = ws_size >= NEED_C;

  const long nWIH = (long)G4 * IN2;
  const long nWHH = (long)G4 * DD;

  if (combined) {
    unsigned short* xg   = (unsigned short*)alloc(SZ_XG_A);
    unsigned short* xbf  = (unsigned short*)alloc(SZ_XBF);   // x input, later reused as outc
    unsigned short* wbuf = (unsigned short*)alloc(SZ_W);     // wih_f -> wih_b -> whh(both)
    float*          bias = (float*)alloc(SZ_BIAS);
    unsigned short* hbuf = (unsigned short*)alloc(SZ_HBUF);
    unsigned*       bar  = (unsigned*)alloc(SZ_BAR);
    float* sums   = (float*)xg;                              // overlay, consumed pre-xg-GEMM
    float* counts = sums + (size_t)VOCAB * DD;

    hipMemsetAsync(sums, 0, SZ_SUMS, stream);
    hipMemsetAsync(bar, 0, SZ_BAR, stream);
    seg_scatter<<<ROWS, 256, 0, stream>>>(batch, hidden, sums, counts);
    build_x<<<ROWS, 256, 0, stream>>>(batch, hidden, sums, counts, xbf);
    conv_bias_perm<<<(NB2 + 255) / 256, 256, 0, stream>>>(b_ih_f, b_hh_f, b_ih_b, b_hh_b, bias);

    for (int dir = 0; dir < 2; dir++) {
      conv_w_perm<<<(unsigned)((nWIH + 255) / 256), 256, 0, stream>>>(dir ? w_ih_b : w_ih_f, wbuf, IN2);
      dim3 grid(G4 / 128, ROWS / 128, 1);
      gemm_bt<<<grid, 256, 0, stream>>>(xbf, IN2, wbuf, IN2,
                                        xg + (size_t)dir * G4, NB2,
                                        bias + (size_t)dir * G4, IN2);
    }
    // wih dead; same buffer now holds whh (both dirs, 9.4 MB)
    conv_w_perm<<<(unsigned)((nWHH + 255) / 256), 256, 0, stream>>>(w_hh_f, wbuf, DD);
    conv_w_perm<<<(unsigned)((nWHH + 255) / 256), 256, 0, stream>>>(w_hh_b, wbuf + (size_t)G4 * DD, DD);

    hipMemsetAsync(hbuf, 0, SZ_HBUF, stream);
    lstm_persist<<<192, 256, 0, stream>>>(xg, NB2, wbuf, hbuf, xbf, bar, 192, 0, 2);
    final_linear<<<ROWS, 256, 0, stream>>>(xbf, lin_w, lin_b, out);
  } else {
    // direction-sequential (~223 MB, proven to fit)
    unsigned short* xg   = (unsigned short*)alloc(SZ_XG_B);
    unsigned short* xbf  = (unsigned short*)alloc(SZ_XBF);
    unsigned short* outc = (unsigned short*)alloc(SZ_XBF);
    unsigned short* wih  = (unsigned short*)alloc(SZ_W);
    unsigned short* whh  = (unsigned short*)alloc(SZ_W);
    float*          bias = (float*)alloc(SZ_BIAS);
    unsigned short* hbuf = (unsigned short*)alloc(SZ_HBUF);
    unsigned*       bar  = (unsigned*)alloc(SZ_BAR);
    float* sums   = (float*)xg;                              // 89.2 MB <= 100.7 MB
    float* counts = sums + (size_t)VOCAB * DD;

    hipMemsetAsync(sums, 0, SZ_SUMS, stream);
    hipMemsetAsync(bar, 0, SZ_BAR, stream);
    seg_scatter<<<ROWS, 256, 0, stream>>>(batch, hidden, sums, counts);
    build_x<<<ROWS, 256, 0, stream>>>(batch, hidden, sums, counts, xbf);
    conv_bias_perm<<<(NB2 + 255) / 256, 256, 0, stream>>>(b_ih_f, b_hh_f, b_ih_b, b_hh_b, bias);
    conv_w_perm<<<(unsigned)((nWHH + 255) / 256), 256, 0, stream>>>(w_hh_f, whh, DD);
    conv_w_perm<<<(unsigned)((nWHH + 255) / 256), 256, 0, stream>>>(w_hh_b, whh + (size_t)G4 * DD, DD);

    for (int dir = 0; dir < 2; dir++) {
      conv_w_perm<<<(unsigned)((nWIH + 255) / 256), 256, 0, stream>>>(dir ? w_ih_b : w_ih_f, wih, IN2);
      {
        dim3 grid(G4 / 128, ROWS / 128, 1);
        gemm_bt<<<grid, 256, 0, stream>>>(xbf, IN2, wih, IN2, xg, G4,
                                          bias + (size_t)dir * G4, IN2);
      }
      hipMemsetAsync(hbuf, 0, SZ_HBUF, stream);
      lstm_persist<<<96, 256, 0, stream>>>(xg, G4, whh, hbuf, outc, bar, 96, dir, 1);
    }
    final_linear<<<ROWS, 256, 0, stream>>>(outc, lin_w, lin_b, out);
  }
}

// Round 5
// 2849.692 us; speedup vs baseline: 1.3785x; 1.3785x over previous
//
#include <hip/hip_runtime.h>

#define VOCAB 28996
#define BB 32
#define SS 512
#define DD 768
#define NCLS 9
#define ROWS (BB*SS)     // 16384
#define IN2 (2*DD)       // 1536
#define G4 (4*DD)        // 3072
#define NB2 (2*G4)       // 6144

typedef __attribute__((ext_vector_type(8))) short short8;
typedef __attribute__((ext_vector_type(4))) float floatx4;
typedef unsigned long long ull;

__device__ __forceinline__ float bf2f(unsigned short u){
  union { unsigned int i; float f; } v; v.i = ((unsigned int)u) << 16; return v.f;
}
__device__ __forceinline__ unsigned short f2bf(float f){
  union { float f; unsigned int i; } v; v.f = f;
  unsigned int r = v.i + 0x7FFFu + ((v.i >> 16) & 1u);
  return (unsigned short)(r >> 16);
}
__device__ __forceinline__ float sigf(float x){ return 1.0f / (1.0f + __expf(-x)); }

__device__ __forceinline__ void gl_lds16(const unsigned short* g, unsigned short* l){
  __builtin_amdgcn_global_load_lds((__attribute__((address_space(1))) void*)(g),
                                   (__attribute__((address_space(3))) void*)(l), 16, 0, 0);
}

// ---- manual grid barrier, cache-friendly ----
// All cross-block data (h) moves via agent-scope RELAXED atomics which bypass the
// non-coherent per-XCD L2 (sc1 -> L3 is the coherence point). Read-only data
// (whh/xg) can never be stale. So NO fences / L2 invalidation needed here:
//  - __syncthreads() drains vmcnt(0) => this block's (bypassing) h-stores are
//    complete at L3 before the leader's arrival RMW issues.
//  - spin uses RELAXED loads (sc1, no buffer_inv per poll -- R4's 10x bug).
//  - winner's gen flip is RELEASE only to order the counter reset before it.
__device__ __forceinline__ void grid_bar(unsigned* bar, int nb)
{
  __syncthreads();
  if (threadIdx.x == 0) {
    unsigned g = __hip_atomic_load(bar + 1, __ATOMIC_RELAXED, __HIP_MEMORY_SCOPE_AGENT);
    unsigned a = __hip_atomic_fetch_add(bar, 1u, __ATOMIC_RELAXED, __HIP_MEMORY_SCOPE_AGENT);
    if (a == (unsigned)(nb - 1)) {
      __hip_atomic_store(bar, 0u, __ATOMIC_RELAXED, __HIP_MEMORY_SCOPE_AGENT);
      __hip_atomic_store(bar + 1, g + 1u, __ATOMIC_RELEASE, __HIP_MEMORY_SCOPE_AGENT);
    } else {
      unsigned cur;
      do {
        __builtin_amdgcn_s_sleep(4);
        cur = __hip_atomic_load(bar + 1, __ATOMIC_RELAXED, __HIP_MEMORY_SCOPE_AGENT);
      } while (cur == g);
    }
  }
  __syncthreads();
}

// ---------------- segment mean ----------------
__global__ void seg_scatter(const int* __restrict__ ids, const float* __restrict__ hidden,
                            float* __restrict__ sums, float* __restrict__ counts)
{
  int r = blockIdx.x;
  int id = ids[r];
  const float* h = hidden + (long)r * DD;
  float* s = sums + (long)id * DD;
  for (int d = threadIdx.x; d < DD; d += 256)
    atomicAdd(&s[d], h[d]);
  if (threadIdx.x == 0) atomicAdd(&counts[id], 1.0f);
}

__global__ void build_x(const int* __restrict__ ids, const float* __restrict__ hidden,
                        const float* __restrict__ sums, const float* __restrict__ counts,
                        unsigned short* __restrict__ x)
{
  int r = blockIdx.x;
  int id = ids[r];
  float inv = 1.0f / fmaxf(counts[id], 1.0f);
  const float* h = hidden + (long)r * DD;
  const float* s = sums + (long)id * DD;
  unsigned short* xr = x + (long)r * IN2;
  for (int d = threadIdx.x; d < DD; d += 256) {
    xr[d]      = f2bf(h[d]);
    xr[DD + d] = f2bf(s[d] * inv);
  }
}

// -------- weight conversion with gate-interleave permutation: row' = u*4+g <- row g*768+u --------
__global__ void conv_w_perm(const float* __restrict__ w, unsigned short* __restrict__ o, int K)
{
  long i = (long)blockIdx.x * 256 + threadIdx.x;   // over 3072*K
  if (i >= (long)G4 * K) return;
  int row = (int)(i / K); int k = (int)(i - (long)row * K);
  int u = row >> 2, g = row & 3;
  o[i] = f2bf(w[((long)(g * DD + u)) * K + k]);
}

__global__ void conv_bias_perm(const float* __restrict__ bif, const float* __restrict__ bhf,
                               const float* __restrict__ bib, const float* __restrict__ bhb,
                               float* __restrict__ o)
{
  int n = blockIdx.x * 256 + threadIdx.x;
  if (n >= NB2) return;
  int d = n / G4, rr = n - d * G4, u = rr >> 2, g = rr & 3;
  int s = g * DD + u;
  o[n] = d ? (bib[s] + bhb[s]) : (bif[s] + bhf[s]);
}

// ---------------- GEMM: C[m,n] = sum_k A[m,k]*B[n,k] + bias[n], bf16 out ----------------
__global__ __launch_bounds__(256, 2)
void gemm_bt(const unsigned short* __restrict__ A, int lda,
             const unsigned short* __restrict__ B, int ldb,
             unsigned short* __restrict__ C, int ldc,
             const float* __restrict__ bias, int K)
{
  __shared__ unsigned short lA[128 * 32];
  __shared__ unsigned short lB[128 * 32];
  const int t = threadIdx.x;
  const int lane = t & 63;
  const int wv = t >> 6;
  const int wm = wv >> 1, wn = wv & 1;
  const int l15 = lane & 15, q = lane >> 4;
  const long m0 = (long)blockIdx.y * 128;
  const long n0 = (long)blockIdx.x * 128;
  const int rowS = t >> 2;
  const int kc = (t & 3) * 8;
  const unsigned short* gA = A + (m0 + rowS) * lda + kc;
  const unsigned short* gB = B + (n0 + rowS) * ldb + kc;
  unsigned short* dA0 = lA + (wv << 9);
  unsigned short* dA1 = lA + 2048 + (wv << 9);
  unsigned short* dB0 = lB + (wv << 9);
  unsigned short* dB1 = lB + 2048 + (wv << 9);

  floatx4 acc[4][4];
  #pragma unroll
  for (int i = 0; i < 4; i++)
    #pragma unroll
    for (int j = 0; j < 4; j++)
      acc[i][j] = (floatx4){0.f, 0.f, 0.f, 0.f};

  const long a64 = (long)64 * lda;
  const long b64 = (long)64 * ldb;
  for (int kt = 0; kt < K; kt += 32) {
    gl_lds16(gA + kt,       dA0);
    gl_lds16(gA + a64 + kt, dA1);
    gl_lds16(gB + kt,       dB0);
    gl_lds16(gB + b64 + kt, dB1);
    __syncthreads();
    short8 af[4], bfr[4];
    #pragma unroll
    for (int i = 0; i < 4; i++)
      af[i] = *(const short8*)(lA + (wm * 64 + i * 16 + l15) * 32 + q * 8);
    #pragma unroll
    for (int j = 0; j < 4; j++)
      bfr[j] = *(const short8*)(lB + (wn * 64 + j * 16 + l15) * 32 + q * 8);
    #pragma unroll
    for (int i = 0; i < 4; i++)
      #pragma unroll
      for (int j = 0; j < 4; j++)
        acc[i][j] = __builtin_amdgcn_mfma_f32_16x16x32_bf16(af[i], bfr[j], acc[i][j], 0, 0, 0);
    __syncthreads();
  }

  #pragma unroll
  for (int i = 0; i < 4; i++) {
    #pragma unroll
    for (int j = 0; j < 4; j++) {
      const long mg = m0 + wm * 64 + i * 16 + q * 4;
      const long ng = n0 + wn * 64 + j * 16 + l15;
      const float bb = bias[ng];
      #pragma unroll
      for (int r = 0; r < 4; r++)
        C[(mg + r) * ldc + ng] = f2bf(acc[i][j][r] + bb);
    }
  }
}

// ---------------- persistent bidirectional LSTM recurrence ----------------
// grid = ndir*96 blocks: per dir, 4 m-tiles x 24 n-tiles (gate-interleaved cols: u*4+g).
// c stays in registers across all 32 steps. h ping-pongs via hbuf using agent-scope
// RELAXED atomics (bypass non-coherent L2, L3 is the coherence point); whh/xg use
// normal cached loads and stay L2-resident (no invalidation anywhere).
__global__ __launch_bounds__(256, 1)
void lstm_persist(const unsigned short* __restrict__ xg, int ldxg,
                  const unsigned short* __restrict__ whh,   // [2][3072][768] permuted, global dir
                  unsigned short* __restrict__ hbuf,        // [2][ndir][512][768]
                  unsigned short* __restrict__ outc,        // [16384][1536]
                  unsigned* bar, int nblocks,
                  int dir0, int ndir)
{
  __shared__ unsigned short lA[128 * 32];
  __shared__ unsigned short lB[128 * 32];
  const int bid = blockIdx.x;
  const int ld = bid / 96;
  const int rr = bid - ld * 96;
  const int mt = rr / 24, nt = rr - (rr / 24) * 24;
  const int dir = dir0 + ld;
  const int t0 = threadIdx.x;
  const int lane = t0 & 63;
  const int wv = t0 >> 6;
  const int wm = wv >> 1, wn = wv & 1;
  const int l15 = lane & 15, q = lane >> 4;
  const int m0 = mt * 128, n0 = nt * 128;
  const int rowS = t0 >> 2;
  const int kc = (t0 & 3) * 8;
  const int baseLane = lane & ~3;

  const unsigned short* Bp = whh + (long)dir * G4 * DD + ((long)(n0 + rowS)) * DD + kc;
  unsigned short* dB0 = lB + (wv << 9);
  unsigned short* dB1 = lB + 2048 + (wv << 9);
  unsigned short* wA0 = lA + rowS * 32 + kc;         // manual A staging (same layout)
  unsigned short* wA1 = lA + (64 + rowS) * 32 + kc;
  const long s64 = (long)64 * DD;

  float c_reg[4][4][4];
  #pragma unroll
  for (int i = 0; i < 4; i++)
    #pragma unroll
    for (int j = 0; j < 4; j++)
      #pragma unroll
      for (int r = 0; r < 4; r++)
        c_reg[i][j][r] = 0.f;

  for (int s = 0; s < BB; s++) {
    const int t = dir ? (BB - 1 - s) : s;
    const unsigned short* Ap = hbuf + (((long)(s & 1)) * ndir + ld) * ((long)SS * DD)
                                    + ((long)(m0 + rowS)) * DD + kc;
    unsigned short* hw = hbuf + (((long)((s + 1) & 1)) * ndir + ld) * ((long)SS * DD);

    floatx4 acc[4][4];
    #pragma unroll
    for (int i = 0; i < 4; i++)
      #pragma unroll
      for (int j = 0; j < 4; j++)
        acc[i][j] = (floatx4){0.f, 0.f, 0.f, 0.f};

    for (int kt = 0; kt < DD; kt += 32) {
      // A (h) via 8B agent-scope relaxed loads: bypass L2 -> always-fresh from L3
      ull a0 = __hip_atomic_load((const ull*)(Ap + kt),           __ATOMIC_RELAXED, __HIP_MEMORY_SCOPE_AGENT);
      ull a1 = __hip_atomic_load((const ull*)(Ap + kt + 4),       __ATOMIC_RELAXED, __HIP_MEMORY_SCOPE_AGENT);
      ull a2 = __hip_atomic_load((const ull*)(Ap + s64 + kt),     __ATOMIC_RELAXED, __HIP_MEMORY_SCOPE_AGENT);
      ull a3 = __hip_atomic_load((const ull*)(Ap + s64 + kt + 4), __ATOMIC_RELAXED, __HIP_MEMORY_SCOPE_AGENT);
      // B (weights, read-only) via cached direct-to-LDS
      gl_lds16(Bp + kt,       dB0);
      gl_lds16(Bp + s64 + kt, dB1);
      *(ull*)wA0       = a0;
      *(ull*)(wA0 + 4) = a1;
      *(ull*)wA1       = a2;
      *(ull*)(wA1 + 4) = a3;
      __syncthreads();
      short8 af[4], bfr[4];
      #pragma unroll
      for (int i = 0; i < 4; i++)
        af[i] = *(const short8*)(lA + (wm * 64 + i * 16 + l15) * 32 + q * 8);
      #pragma unroll
      for (int j = 0; j < 4; j++)
        bfr[j] = *(const short8*)(lB + (wn * 64 + j * 16 + l15) * 32 + q * 8);
      #pragma unroll
      for (int i = 0; i < 4; i++)
        #pragma unroll
        for (int j = 0; j < 4; j++)
          acc[i][j] = __builtin_amdgcn_mfma_f32_16x16x32_bf16(af[i], bfr[j], acc[i][j], 0, 0, 0);
      __syncthreads();
    }

    // fused gate epilogue
    const unsigned short* xgp = xg + ((long)t * SS) * ldxg + (long)ld * G4;
    #pragma unroll
    for (int i = 0; i < 4; i++) {
      #pragma unroll
      for (int j = 0; j < 4; j++) {
        const int mg = m0 + wm * 64 + i * 16 + q * 4;
        const int ng = n0 + wn * 64 + j * 16 + l15;
        const int u  = ng >> 2;
        #pragma unroll
        for (int r = 0; r < 4; r++) {
          float v = acc[i][j][r] + bf2f(xgp[((long)(mg + r)) * ldxg + ng]);
          float gi = __shfl(v, baseLane + 0, 64);
          float gf = __shfl(v, baseLane + 1, 64);
          float gg = __shfl(v, baseLane + 2, 64);
          float go = __shfl(v, baseLane + 3, 64);
          float c = sigf(gf) * c_reg[i][j][r] + sigf(gi) * tanhf(gg);
          float h = sigf(go) * tanhf(c);
          c_reg[i][j][r] = c;
          if ((l15 & 3) == 0) {
            unsigned short hb = f2bf(h);
            // h store bypasses L2 (agent relaxed) -> visible at L3 to all XCDs
            __hip_atomic_store(&hw[((long)(mg + r)) * DD + u], hb,
                               __ATOMIC_RELAXED, __HIP_MEMORY_SCOPE_AGENT);
            outc[((long)(t * SS + mg + r)) * IN2 + dir * DD + u] = hb;
          }
        }
      }
    }
    if (s < BB - 1) grid_bar(bar, nblocks);
  }
}

// ---------------- final linear [16384,1536](bf16) x [9,1536]^T ----------------
__global__ void final_linear(const unsigned short* __restrict__ xin, const float* __restrict__ w,
                             const float* __restrict__ b, float* __restrict__ out)
{
  __shared__ float red[NCLS * 256];
  int row = blockIdx.x;
  const unsigned short* x = xin + (long)row * IN2;
  float p[NCLS];
  #pragma unroll
  for (int c = 0; c < NCLS; c++) p[c] = 0.f;
  for (int k = threadIdx.x; k < IN2; k += 256) {
    float xv = bf2f(x[k]);
    #pragma unroll
    for (int c = 0; c < NCLS; c++) p[c] += xv * w[c * IN2 + k];
  }
  #pragma unroll
  for (int c = 0; c < NCLS; c++) red[c * 256 + threadIdx.x] = p[c];
  __syncthreads();
  for (int s = 128; s > 0; s >>= 1) {
    if (threadIdx.x < s) {
      #pragma unroll
      for (int c = 0; c < NCLS; c++)
        red[c * 256 + threadIdx.x] += red[c * 256 + threadIdx.x + s];
    }
    __syncthreads();
  }
  if (threadIdx.x < NCLS)
    out[(long)row * NCLS + threadIdx.x] = red[threadIdx.x * 256] + b[threadIdx.x];
}

extern "C" void kernel_launch(void* const* d_in, const int* in_sizes, int n_in,
                              void* d_out, int out_size, void* d_ws, size_t ws_size,
                              hipStream_t stream)
{
  const int*   batch  = (const int*)d_in[0];
  const float* hidden = (const float*)d_in[1];
  const float* w_ih_f = (const float*)d_in[2];
  const float* w_hh_f = (const float*)d_in[3];
  const float* b_ih_f = (const float*)d_in[4];
  const float* b_hh_f = (const float*)d_in[5];
  const float* w_ih_b = (const float*)d_in[6];
  const float* w_hh_b = (const float*)d_in[7];
  const float* b_ih_b = (const float*)d_in[8];
  const float* b_hh_b = (const float*)d_in[9];
  const float* lin_w  = (const float*)d_in[10];
  const float* lin_b  = (const float*)d_in[11];
  float* out = (float*)d_out;

  char* ws = (char*)d_ws;
  size_t off = 0;
  auto alloc = [&](size_t bytes) -> char* {
    char* p = ws + off;
    off += (bytes + 255) & ~(size_t)255;
    return p;
  };

  const size_t SZ_XG_A = (size_t)ROWS * NB2 * 2;      // 201.3 MB
  const size_t SZ_XG_B = (size_t)ROWS * G4  * 2;      // 100.7 MB
  const size_t SZ_XBF  = (size_t)ROWS * IN2 * 2;      //  50.3 MB
  const size_t SZ_W    = (size_t)G4 * IN2 * 2;        //   9.4 MB (== 2*G4*DD*2)
  const size_t SZ_BIAS = (size_t)NB2 * 4;
  const size_t SZ_HBUF = (size_t)2 * 2 * SS * DD * 2; //   3.1 MB
  const size_t SZ_BAR  = 256;
  const size_t SZ_SUMS = (size_t)VOCAB * DD * 4 + (size_t)VOCAB * 4;

  // combined layout: xg(both dirs) + xbf/outc + shared w buffer + bias + hbuf + bar  ~= 264.3 MB
  const size_t NEED_C = SZ_XG_A + SZ_XBF + SZ_W + SZ_BIAS + SZ_HBUF + SZ_BAR + 8 * 256;
  const bool combined = ws_size >= NEED_C;

  const long nWIH = (long)G4 * IN2;
  const long nWHH = (long)G4 * DD;

  if (combined) {
    unsigned short* xg   = (unsigned short*)alloc(SZ_XG_A);
    unsigned short* xbf  = (unsigned short*)alloc(SZ_XBF);   // x input, later reused as outc
    unsigned short* wbuf = (unsigned short*)alloc(SZ_W);     // wih_f -> wih_b -> whh(both)
    float*          bias = (float*)alloc(SZ_BIAS);
    unsigned short* hbuf = (unsigned short*)alloc(SZ_HBUF);
    unsigned*       bar  = (unsigned*)alloc(SZ_BAR);
    float* sums   = (float*)xg;                              // overlay, consumed pre-xg-GEMM
    float* counts = sums + (size_t)VOCAB * DD;

    hipMemsetAsync(sums, 0, SZ_SUMS, stream);
    hipMemsetAsync(bar, 0, SZ_BAR, stream);
    seg_scatter<<<ROWS, 256, 0, stream>>>(batch, hidden, sums, counts);
    build_x<<<ROWS, 256, 0, stream>>>(batch, hidden, sums, counts, xbf);
    conv_bias_perm<<<(NB2 + 255) / 256, 256, 0, stream>>>(b_ih_f, b_hh_f, b_ih_b, b_hh_b, bias);

    for (int dir = 0; dir < 2; dir++) {
      conv_w_perm<<<(unsigned)((nWIH + 255) / 256), 256, 0, stream>>>(dir ? w_ih_b : w_ih_f, wbuf, IN2);
      dim3 grid(G4 / 128, ROWS / 128, 1);
      gemm_bt<<<grid, 256, 0, stream>>>(xbf, IN2, wbuf, IN2,
                                        xg + (size_t)dir * G4, NB2,
                                        bias + (size_t)dir * G4, IN2);
    }
    // wih dead; same buffer now holds whh (both dirs, 9.4 MB)
    conv_w_perm<<<(unsigned)((nWHH + 255) / 256), 256, 0, stream>>>(w_hh_f, wbuf, DD);
    conv_w_perm<<<(unsigned)((nWHH + 255) / 256), 256, 0, stream>>>(w_hh_b, wbuf + (size_t)G4 * DD, DD);

    hipMemsetAsync(hbuf, 0, SZ_HBUF, stream);
    lstm_persist<<<192, 256, 0, stream>>>(xg, NB2, wbuf, hbuf, xbf, bar, 192, 0, 2);
    final_linear<<<ROWS, 256, 0, stream>>>(xbf, lin_w, lin_b, out);
  } else {
    // direction-sequential (~223 MB, proven to fit)
    unsigned short* xg   = (unsigned short*)alloc(SZ_XG_B);
    unsigned short* xbf  = (unsigned short*)alloc(SZ_XBF);
    unsigned short* outc = (unsigned short*)alloc(SZ_XBF);
    unsigned short* wih  = (unsigned short*)alloc(SZ_W);
    unsigned short* whh  = (unsigned short*)alloc(SZ_W);
    float*          bias = (float*)alloc(SZ_BIAS);
    unsigned short* hbuf = (unsigned short*)alloc(SZ_HBUF);
    unsigned*       bar  = (unsigned*)alloc(SZ_BAR);
    float* sums   = (float*)xg;                              // 89.2 MB <= 100.7 MB
    float* counts = sums + (size_t)VOCAB * DD;

    hipMemsetAsync(sums, 0, SZ_SUMS, stream);
    hipMemsetAsync(bar, 0, SZ_BAR, stream);
    seg_scatter<<<ROWS, 256, 0, stream>>>(batch, hidden, sums, counts);
    build_x<<<ROWS, 256, 0, stream>>>(batch, hidden, sums, counts, xbf);
    conv_bias_perm<<<(NB2 + 255) / 256, 256, 0, stream>>>(b_ih_f, b_hh_f, b_ih_b, b_hh_b, bias);
    conv_w_perm<<<(unsigned)((nWHH + 255) / 256), 256, 0, stream>>>(w_hh_f, whh, DD);
    conv_w_perm<<<(unsigned)((nWHH + 255) / 256), 256, 0, stream>>>(w_hh_b, whh + (size_t)G4 * DD, DD);

    for (int dir = 0; dir < 2; dir++) {
      conv_w_perm<<<(unsigned)((nWIH + 255) / 256), 256, 0, stream>>>(dir ? w_ih_b : w_ih_f, wih, IN2);
      {
        dim3 grid(G4 / 128, ROWS / 128, 1);
        gemm_bt<<<grid, 256, 0, stream>>>(xbf, IN2, wih, IN2, xg, G4,
                                          bias + (size_t)dir * G4, IN2);
      }
      hipMemsetAsync(hbuf, 0, SZ_HBUF, stream);
      lstm_persist<<<96, 256, 0, stream>>>(xg, G4, whh, hbuf, outc, bar, 96, dir, 1);
    }
    final_linear<<<ROWS, 256, 0, stream>>>(outc, lin_w, lin_b, out);
  }
}

// Round 6
// 2303.792 us; speedup vs baseline: 1.7052x; 1.2370x over previous
//
#include <hip/hip_runtime.h>

#define VOCAB 28996
#define BB 32
#define SS 512
#define DD 768
#define NCLS 9
#define ROWS (BB*SS)     // 16384
#define IN2 (2*DD)       // 1536
#define G4 (4*DD)        // 3072
#define NB2 (2*G4)       // 6144

typedef __attribute__((ext_vector_type(8))) short short8;
typedef __attribute__((ext_vector_type(4))) float floatx4;
typedef unsigned long long ull;

__device__ __forceinline__ float bf2f(unsigned short u){
  union { unsigned int i; float f; } v; v.i = ((unsigned int)u) << 16; return v.f;
}
__device__ __forceinline__ unsigned short f2bf(float f){
  union { float f; unsigned int i; } v; v.f = f;
  unsigned int r = v.i + 0x7FFFu + ((v.i >> 16) & 1u);
  return (unsigned short)(r >> 16);
}
__device__ __forceinline__ float sigf(float x){ return 1.0f / (1.0f + __expf(-x)); }
__device__ __forceinline__ float tanhfast(float x){
  float y = fminf(fmaxf(x, -15.f), 15.f);
  float e = __expf(2.f * y);
  return 1.f - 2.f / (e + 1.f);
}

__device__ __forceinline__ void gl_lds16(const unsigned short* g, unsigned short* l){
  __builtin_amdgcn_global_load_lds((__attribute__((address_space(1))) void*)(g),
                                   (__attribute__((address_space(3))) void*)(l), 16, 0, 0);
}

// ---- group barrier: relaxed sc1 atomics only (no L2 invalidation; R5-proven) ----
__device__ __forceinline__ void grid_bar(unsigned* bar, int nb)
{
  __syncthreads();   // drains this block's vm ops (incl. sc1 h-stores) before arrival
  if (threadIdx.x == 0) {
    unsigned g = __hip_atomic_load(bar + 1, __ATOMIC_RELAXED, __HIP_MEMORY_SCOPE_AGENT);
    unsigned a = __hip_atomic_fetch_add(bar, 1u, __ATOMIC_RELAXED, __HIP_MEMORY_SCOPE_AGENT);
    if (a == (unsigned)(nb - 1)) {
      __hip_atomic_store(bar, 0u, __ATOMIC_RELAXED, __HIP_MEMORY_SCOPE_AGENT);
      __hip_atomic_store(bar + 1, g + 1u, __ATOMIC_RELEASE, __HIP_MEMORY_SCOPE_AGENT);
    } else {
      unsigned cur;
      do {
        __builtin_amdgcn_s_sleep(2);
        cur = __hip_atomic_load(bar + 1, __ATOMIC_RELAXED, __HIP_MEMORY_SCOPE_AGENT);
      } while (cur == g);
    }
  }
  __syncthreads();
}

// ---------------- segment mean ----------------
__global__ void seg_scatter(const int* __restrict__ ids, const float* __restrict__ hidden,
                            float* __restrict__ sums, float* __restrict__ counts)
{
  int r = blockIdx.x;
  int id = ids[r];
  const float* h = hidden + (long)r * DD;
  float* s = sums + (long)id * DD;
  for (int d = threadIdx.x; d < DD; d += 256)
    atomicAdd(&s[d], h[d]);
  if (threadIdx.x == 0) atomicAdd(&counts[id], 1.0f);
}

__global__ void build_x(const int* __restrict__ ids, const float* __restrict__ hidden,
                        const float* __restrict__ sums, const float* __restrict__ counts,
                        unsigned short* __restrict__ x)
{
  int r = blockIdx.x;
  int id = ids[r];
  float inv = 1.0f / fmaxf(counts[id], 1.0f);
  const float* h = hidden + (long)r * DD;
  const float* s = sums + (long)id * DD;
  unsigned short* xr = x + (long)r * IN2;
  for (int d = threadIdx.x; d < DD; d += 256) {
    xr[d]      = f2bf(h[d]);
    xr[DD + d] = f2bf(s[d] * inv);
  }
}

// -------- weight conversion with gate-interleave permutation: row' = u*4+g <- row g*768+u --------
__global__ void conv_w_perm(const float* __restrict__ w, unsigned short* __restrict__ o, int K)
{
  long i = (long)blockIdx.x * 256 + threadIdx.x;
  if (i >= (long)G4 * K) return;
  int row = (int)(i / K); int k = (int)(i - (long)row * K);
  int u = row >> 2, g = row & 3;
  o[i] = f2bf(w[((long)(g * DD + u)) * K + k]);
}

__global__ void conv_bias_perm(const float* __restrict__ bif, const float* __restrict__ bhf,
                               const float* __restrict__ bib, const float* __restrict__ bhb,
                               float* __restrict__ o)
{
  int n = blockIdx.x * 256 + threadIdx.x;
  if (n >= NB2) return;
  int d = n / G4, rr = n - d * G4, u = rr >> 2, g = rr & 3;
  int s = g * DD + u;
  o[n] = d ? (bib[s] + bhb[s]) : (bif[s] + bhf[s]);
}

// ---------------- GEMM: C[m,n] = sum_k A[m,k]*B[n,k] + bias[n], bf16 out ----------------
__global__ __launch_bounds__(256, 2)
void gemm_bt(const unsigned short* __restrict__ A, int lda,
             const unsigned short* __restrict__ B, int ldb,
             unsigned short* __restrict__ C, int ldc,
             const float* __restrict__ bias, int K)
{
  __shared__ unsigned short lA[128 * 32];
  __shared__ unsigned short lB[128 * 32];
  const int t = threadIdx.x;
  const int lane = t & 63;
  const int wv = t >> 6;
  const int wm = wv >> 1, wn = wv & 1;
  const int l15 = lane & 15, q = lane >> 4;
  const long m0 = (long)blockIdx.y * 128;
  const long n0 = (long)blockIdx.x * 128;
  const int rowS = t >> 2;
  const int kc = (t & 3) * 8;
  const unsigned short* gA = A + (m0 + rowS) * lda + kc;
  const unsigned short* gB = B + (n0 + rowS) * ldb + kc;
  unsigned short* dA0 = lA + (wv << 9);
  unsigned short* dA1 = lA + 2048 + (wv << 9);
  unsigned short* dB0 = lB + (wv << 9);
  unsigned short* dB1 = lB + 2048 + (wv << 9);

  floatx4 acc[4][4];
  #pragma unroll
  for (int i = 0; i < 4; i++)
    #pragma unroll
    for (int j = 0; j < 4; j++)
      acc[i][j] = (floatx4){0.f, 0.f, 0.f, 0.f};

  const long a64 = (long)64 * lda;
  const long b64 = (long)64 * ldb;
  for (int kt = 0; kt < K; kt += 32) {
    gl_lds16(gA + kt,       dA0);
    gl_lds16(gA + a64 + kt, dA1);
    gl_lds16(gB + kt,       dB0);
    gl_lds16(gB + b64 + kt, dB1);
    __syncthreads();
    short8 af[4], bfr[4];
    #pragma unroll
    for (int i = 0; i < 4; i++)
      af[i] = *(const short8*)(lA + (wm * 64 + i * 16 + l15) * 32 + q * 8);
    #pragma unroll
    for (int j = 0; j < 4; j++)
      bfr[j] = *(const short8*)(lB + (wn * 64 + j * 16 + l15) * 32 + q * 8);
    #pragma unroll
    for (int i = 0; i < 4; i++)
      #pragma unroll
      for (int j = 0; j < 4; j++)
        acc[i][j] = __builtin_amdgcn_mfma_f32_16x16x32_bf16(af[i], bfr[j], acc[i][j], 0, 0, 0);
    __syncthreads();
  }

  #pragma unroll
  for (int i = 0; i < 4; i++) {
    #pragma unroll
    for (int j = 0; j < 4; j++) {
      const long mg = m0 + wm * 64 + i * 16 + q * 4;
      const long ng = n0 + wn * 64 + j * 16 + l15;
      const float bb = bias[ng];
      #pragma unroll
      for (int r = 0; r < 4; r++)
        C[(mg + r) * ldc + ng] = f2bf(acc[i][j][r] + bb);
    }
  }
}

// ---------------- persistent bidirectional LSTM recurrence ----------------
// XCD-aware mapping: xcd = bid&7, nt = k3*8+xcd -> per-XCD whh working set = 6 tiles
// (1.18 MB), L2-resident. BK=128 (6 K-iters/step), LDS panels [ks][128][32].
// xg tile staged to LDS via global_load_lds. Per-(dir,mt) group barriers (24 blocks).
__global__ __launch_bounds__(256, 1)
void lstm_persist(const unsigned short* __restrict__ xg, int ldxg,
                  const unsigned short* __restrict__ whh,   // [2][3072][768] permuted
                  unsigned short* __restrict__ hbuf,        // [2][ndir][512][768]
                  unsigned short* __restrict__ outc,        // [16384][1536]
                  unsigned* bar,                            // 8 groups x 16 u32
                  int dir0, int ndir)
{
  __shared__ unsigned short bufA[16384];   // 4 panels [128][32]
  __shared__ unsigned short bufB[16384];   // 4 panels [128][32]
  __shared__ unsigned short xgs[16384];    // [128 rows][128 gate-cols]

  const int bid = blockIdx.x;
  const int xcd = bid & 7;
  const int idx = bid >> 3;
  int dm, k3;
  if (ndir == 2) { dm = idx & 7; k3 = idx >> 3; }
  else           { dm = idx & 3; k3 = idx >> 2; }
  const int ld  = (ndir == 2) ? (dm & 1) : 0;
  const int dir = dir0 + ld;
  const int mt  = (ndir == 2) ? (dm >> 1) : dm;
  const int nt  = k3 * 8 + xcd;
  const int m0 = mt * 128, n0 = nt * 128;
  unsigned* gbar = bar + dm * 16;

  const int t0 = threadIdx.x;
  const int lane = t0 & 63;
  const int wv = t0 >> 6;
  const int wm = wv >> 1, wn = wv & 1;
  const int l15 = lane & 15, q = lane >> 4;
  const int baseLane = lane & ~3;
  const int arow = t0 >> 1;        // A-staging row 0..127
  const int ah   = t0 & 1;         // which 64-element half
  const long ldoff = (ndir == 2 && ld == 1) ? (long)G4 : 0;

  const unsigned short* Bdir = whh + (long)dir * G4 * DD;

  float c_reg[4][4][4];
  #pragma unroll
  for (int i = 0; i < 4; i++)
    #pragma unroll
    for (int j = 0; j < 4; j++)
      #pragma unroll
      for (int r = 0; r < 4; r++)
        c_reg[i][j][r] = 0.f;

  for (int s = 0; s < BB; s++) {
    const int tt = dir ? (BB - 1 - s) : s;
    const unsigned short* hRead = hbuf + (((long)(s & 1)) * ndir + ld) * ((long)SS * DD);
    unsigned short* hw = hbuf + (((long)((s + 1) & 1)) * ndir + ld) * ((long)SS * DD);

    // stage xg tile [128 rows][128 cols] -> LDS (coalesced 16B direct-to-LDS)
    {
      const unsigned short* xrow = xg + ((long)tt * SS + m0) * ldxg + ldoff + n0;
      #pragma unroll
      for (int c = 0; c < 8; c++) {
        int row = c * 16 + (t0 >> 4);
        gl_lds16(xrow + (long)row * ldxg + (t0 & 15) * 8,
                 xgs + c * 2048 + wv * 512 + lane * 8);
      }
    }

    floatx4 acc[4][4];
    #pragma unroll
    for (int i = 0; i < 4; i++)
      #pragma unroll
      for (int j = 0; j < 4; j++)
        acc[i][j] = (floatx4){0.f, 0.f, 0.f, 0.f};

    for (int kt = 0; kt < 6; kt++) {
      const int kb = kt << 7;
      // B (whh, L2-resident): 8 direct-to-LDS 16B instrs, panel layout
      #pragma unroll
      for (int p = 0; p < 4; p++)
        #pragma unroll
        for (int rbh = 0; rbh < 2; rbh++) {
          int rb = (wv * 2 + rbh) * 16 + (lane >> 2);
          gl_lds16(Bdir + (long)(n0 + rb) * DD + kb + p * 32 + (lane & 3) * 8,
                   bufB + p * 4096 + (wv * 2 + rbh) * 512 + lane * 8);
        }
      // A (h, cross-XCD fresh via sc1): 16x8B atomic loads -> LDS panels
      {
        const unsigned short* Arow = hRead + (long)(m0 + arow) * DD + kb + ah * 64;
        ull av[16];
        #pragma unroll
        for (int e = 0; e < 16; e++)
          av[e] = __hip_atomic_load((const ull*)(Arow + e * 4),
                                    __ATOMIC_RELAXED, __HIP_MEMORY_SCOPE_AGENT);
        #pragma unroll
        for (int seg = 0; seg < 2; seg++) {
          unsigned short* dst = bufA + (2 * ah + seg) * 4096 + arow * 32;
          #pragma unroll
          for (int q2 = 0; q2 < 8; q2++)
            *(ull*)(dst + q2 * 4) = av[seg * 8 + q2];
        }
      }
      __syncthreads();
      #pragma unroll
      for (int ks = 0; ks < 4; ks++) {
        short8 af[4], bfr[4];
        #pragma unroll
        for (int i = 0; i < 4; i++)
          af[i] = *(const short8*)(bufA + ks * 4096 + (wm * 64 + i * 16 + l15) * 32 + q * 8);
        #pragma unroll
        for (int j = 0; j < 4; j++)
          bfr[j] = *(const short8*)(bufB + ks * 4096 + (wn * 64 + j * 16 + l15) * 32 + q * 8);
        #pragma unroll
        for (int i = 0; i < 4; i++)
          #pragma unroll
          for (int j = 0; j < 4; j++)
            acc[i][j] = __builtin_amdgcn_mfma_f32_16x16x32_bf16(af[i], bfr[j], acc[i][j], 0, 0, 0);
      }
      __syncthreads();
    }

    // fused gate epilogue (xg from LDS)
    #pragma unroll
    for (int i = 0; i < 4; i++) {
      #pragma unroll
      for (int j = 0; j < 4; j++) {
        const int mgl = wm * 64 + i * 16 + q * 4;
        const int ngl = wn * 64 + j * 16 + l15;
        const int u  = (n0 + ngl) >> 2;
        #pragma unroll
        for (int r = 0; r < 4; r++) {
          float v = acc[i][j][r] + bf2f(xgs[(mgl + r) * 128 + ngl]);
          float gi = __shfl(v, baseLane + 0, 64);
          float gf = __shfl(v, baseLane + 1, 64);
          float gg = __shfl(v, baseLane + 2, 64);
          float go = __shfl(v, baseLane + 3, 64);
          float c = sigf(gf) * c_reg[i][j][r] + sigf(gi) * tanhfast(gg);
          float h = sigf(go) * tanhfast(c);
          c_reg[i][j][r] = c;
          if ((l15 & 3) == 0) {
            unsigned short hb = f2bf(h);
            __hip_atomic_store(&hw[((long)(m0 + mgl + r)) * DD + u], hb,
                               __ATOMIC_RELAXED, __HIP_MEMORY_SCOPE_AGENT);
            outc[((long)(tt * SS + m0 + mgl + r)) * IN2 + dir * DD + u] = hb;
          }
        }
      }
    }
    if (s < BB - 1) grid_bar(gbar, 24);
  }
}

// ---------------- final linear [16384,1536](bf16) x [9,1536]^T ----------------
__global__ void final_linear(const unsigned short* __restrict__ xin, const float* __restrict__ w,
                             const float* __restrict__ b, float* __restrict__ out)
{
  __shared__ float red[NCLS * 256];
  int row = blockIdx.x;
  const unsigned short* x = xin + (long)row * IN2;
  float p[NCLS];
  #pragma unroll
  for (int c = 0; c < NCLS; c++) p[c] = 0.f;
  for (int k = threadIdx.x; k < IN2; k += 256) {
    float xv = bf2f(x[k]);
    #pragma unroll
    for (int c = 0; c < NCLS; c++) p[c] += xv * w[c * IN2 + k];
  }
  #pragma unroll
  for (int c = 0; c < NCLS; c++) red[c * 256 + threadIdx.x] = p[c];
  __syncthreads();
  for (int s = 128; s > 0; s >>= 1) {
    if (threadIdx.x < s) {
      #pragma unroll
      for (int c = 0; c < NCLS; c++)
        red[c * 256 + threadIdx.x] += red[c * 256 + threadIdx.x + s];
    }
    __syncthreads();
  }
  if (threadIdx.x < NCLS)
    out[(long)row * NCLS + threadIdx.x] = red[threadIdx.x * 256] + b[threadIdx.x];
}

extern "C" void kernel_launch(void* const* d_in, const int* in_sizes, int n_in,
                              void* d_out, int out_size, void* d_ws, size_t ws_size,
                              hipStream_t stream)
{
  const int*   batch  = (const int*)d_in[0];
  const float* hidden = (const float*)d_in[1];
  const float* w_ih_f = (const float*)d_in[2];
  const float* w_hh_f = (const float*)d_in[3];
  const float* b_ih_f = (const float*)d_in[4];
  const float* b_hh_f = (const float*)d_in[5];
  const float* w_ih_b = (const float*)d_in[6];
  const float* w_hh_b = (const float*)d_in[7];
  const float* b_ih_b = (const float*)d_in[8];
  const float* b_hh_b = (const float*)d_in[9];
  const float* lin_w  = (const float*)d_in[10];
  const float* lin_b  = (const float*)d_in[11];
  float* out = (float*)d_out;

  char* ws = (char*)d_ws;
  size_t off = 0;
  auto alloc = [&](size_t bytes) -> char* {
    char* p = ws + off;
    off += (bytes + 255) & ~(size_t)255;
    return p;
  };

  const size_t SZ_XG_A = (size_t)ROWS * NB2 * 2;      // 201.3 MB
  const size_t SZ_XG_B = (size_t)ROWS * G4  * 2;      // 100.7 MB
  const size_t SZ_XBF  = (size_t)ROWS * IN2 * 2;      //  50.3 MB
  const size_t SZ_W    = (size_t)G4 * IN2 * 2;        //   9.4 MB
  const size_t SZ_BIAS = (size_t)NB2 * 4;
  const size_t SZ_HBUF = (size_t)2 * 2 * SS * DD * 2; //   3.1 MB
  const size_t SZ_BAR  = 512;
  const size_t SZ_SUMS = (size_t)VOCAB * DD * 4 + (size_t)VOCAB * 4;

  const size_t NEED_C = SZ_XG_A + SZ_XBF + SZ_W + SZ_BIAS + SZ_HBUF + SZ_BAR + 8 * 256;
  const bool combined = ws_size >= NEED_C;

  const long nWIH = (long)G4 * IN2;
  const long nWHH = (long)G4 * DD;

  if (combined) {
    unsigned short* xg   = (unsigned short*)alloc(SZ_XG_A);
    unsigned short* xbf  = (unsigned short*)alloc(SZ_XBF);   // x input, later reused as outc
    unsigned short* wbuf = (unsigned short*)alloc(SZ_W);     // wih_f -> wih_b -> whh(both)
    float*          bias = (float*)alloc(SZ_BIAS);
    unsigned short* hbuf = (unsigned short*)alloc(SZ_HBUF);
    unsigned*       bar  = (unsigned*)alloc(SZ_BAR);
    float* sums   = (float*)xg;                              // overlay, consumed pre-xg-GEMM
    float* counts = sums + (size_t)VOCAB * DD;

    hipMemsetAsync(sums, 0, SZ_SUMS, stream);
    hipMemsetAsync(bar, 0, SZ_BAR, stream);
    seg_scatter<<<ROWS, 256, 0, stream>>>(batch, hidden, sums, counts);
    build_x<<<ROWS, 256, 0, stream>>>(batch, hidden, sums, counts, xbf);
    conv_bias_perm<<<(NB2 + 255) / 256, 256, 0, stream>>>(b_ih_f, b_hh_f, b_ih_b, b_hh_b, bias);

    for (int dir = 0; dir < 2; dir++) {
      conv_w_perm<<<(unsigned)((nWIH + 255) / 256), 256, 0, stream>>>(dir ? w_ih_b : w_ih_f, wbuf, IN2);
      dim3 grid(G4 / 128, ROWS / 128, 1);
      gemm_bt<<<grid, 256, 0, stream>>>(xbf, IN2, wbuf, IN2,
                                        xg + (size_t)dir * G4, NB2,
                                        bias + (size_t)dir * G4, IN2);
    }
    conv_w_perm<<<(unsigned)((nWHH + 255) / 256), 256, 0, stream>>>(w_hh_f, wbuf, DD);
    conv_w_perm<<<(unsigned)((nWHH + 255) / 256), 256, 0, stream>>>(w_hh_b, wbuf + (size_t)G4 * DD, DD);

    hipMemsetAsync(hbuf, 0, SZ_HBUF, stream);
    lstm_persist<<<192, 256, 0, stream>>>(xg, NB2, wbuf, hbuf, xbf, bar, 0, 2);
    final_linear<<<ROWS, 256, 0, stream>>>(xbf, lin_w, lin_b, out);
  } else {
    // direction-sequential (~223 MB, proven to fit)
    unsigned short* xg   = (unsigned short*)alloc(SZ_XG_B);
    unsigned short* xbf  = (unsigned short*)alloc(SZ_XBF);
    unsigned short* outc = (unsigned short*)alloc(SZ_XBF);
    unsigned short* wih  = (unsigned short*)alloc(SZ_W);
    unsigned short* whh  = (unsigned short*)alloc(SZ_W);
    float*          bias = (float*)alloc(SZ_BIAS);
    unsigned short* hbuf = (unsigned short*)alloc(SZ_HBUF);
    unsigned*       bar  = (unsigned*)alloc(SZ_BAR);
    float* sums   = (float*)xg;
    float* counts = sums + (size_t)VOCAB * DD;

    hipMemsetAsync(sums, 0, SZ_SUMS, stream);
    hipMemsetAsync(bar, 0, SZ_BAR, stream);
    seg_scatter<<<ROWS, 256, 0, stream>>>(batch, hidden, sums, counts);
    build_x<<<ROWS, 256, 0, stream>>>(batch, hidden, sums, counts, xbf);
    conv_bias_perm<<<(NB2 + 255) / 256, 256, 0, stream>>>(b_ih_f, b_hh_f, b_ih_b, b_hh_b, bias);
    conv_w_perm<<<(unsigned)((nWHH + 255) / 256), 256, 0, stream>>>(w_hh_f, whh, DD);
    conv_w_perm<<<(unsigned)((nWHH + 255) / 256), 256, 0, stream>>>(w_hh_b, whh + (size_t)G4 * DD, DD);

    for (int dir = 0; dir < 2; dir++) {
      conv_w_perm<<<(unsigned)((nWIH + 255) / 256), 256, 0, stream>>>(dir ? w_ih_b : w_ih_f, wih, IN2);
      {
        dim3 grid(G4 / 128, ROWS / 128, 1);
        gemm_bt<<<grid, 256, 0, stream>>>(xbf, IN2, wih, IN2, xg, G4,
                                          bias + (size_t)dir * G4, IN2);
      }
      hipMemsetAsync(hbuf, 0, SZ_HBUF, stream);
      lstm_persist<<<96, 256, 0, stream>>>(xg, G4, whh, hbuf, outc, bar, dir, 1);
    }
    final_linear<<<ROWS, 256, 0, stream>>>(outc, lin_w, lin_b, out);
  }
}

// Round 7
// 1877.141 us; speedup vs baseline: 2.0928x; 1.2273x over previous
//
#include <hip/hip_runtime.h>

#define VOCAB 28996
#define BB 32
#define SS 512
#define DD 768
#define NCLS 9
#define ROWS (BB*SS)     // 16384
#define IN2 (2*DD)       // 1536
#define G4 (4*DD)        // 3072
#define NB2 (2*G4)       // 6144

typedef __attribute__((ext_vector_type(8))) short short8;
typedef __attribute__((ext_vector_type(4))) float floatx4;
typedef unsigned long long ull;

__device__ __forceinline__ float bf2f(unsigned short u){
  union { unsigned int i; float f; } v; v.i = ((unsigned int)u) << 16; return v.f;
}
__device__ __forceinline__ unsigned short f2bf(float f){
  union { float f; unsigned int i; } v; v.f = f;
  unsigned int r = v.i + 0x7FFFu + ((v.i >> 16) & 1u);
  return (unsigned short)(r >> 16);
}
__device__ __forceinline__ float sigf(float x){ return 1.0f / (1.0f + __expf(-x)); }
__device__ __forceinline__ float tanhfast(float x){
  float y = fminf(fmaxf(x, -15.f), 15.f);
  float e = __expf(2.f * y);
  return 1.f - 2.f / (e + 1.f);
}

__device__ __forceinline__ void gl_lds16(const unsigned short* g, unsigned short* l){
  __builtin_amdgcn_global_load_lds((__attribute__((address_space(1))) void*)(g),
                                   (__attribute__((address_space(3))) void*)(l), 16, 0, 0);
}

// ---- group barrier: relaxed sc1 atomics for arrival/spin (no per-poll invalidation,
// R5-proven), then ONE agent-acquire fence (single buffer_inv) to refresh L2 so the
// subsequent plain cached h-loads see the producers' sc1 (L3) stores. ----
__device__ __forceinline__ void grid_bar_acq(unsigned* bar, int nb)
{
  __syncthreads();   // drains this block's vm ops (incl. sc1 h-stores) before arrival
  if (threadIdx.x == 0) {
    unsigned g = __hip_atomic_load(bar + 1, __ATOMIC_RELAXED, __HIP_MEMORY_SCOPE_AGENT);
    unsigned a = __hip_atomic_fetch_add(bar, 1u, __ATOMIC_RELAXED, __HIP_MEMORY_SCOPE_AGENT);
    if (a == (unsigned)(nb - 1)) {
      __hip_atomic_store(bar, 0u, __ATOMIC_RELAXED, __HIP_MEMORY_SCOPE_AGENT);
      __hip_atomic_store(bar + 1, g + 1u, __ATOMIC_RELEASE, __HIP_MEMORY_SCOPE_AGENT);
    } else {
      unsigned cur;
      do {
        __builtin_amdgcn_s_sleep(2);
        cur = __hip_atomic_load(bar + 1, __ATOMIC_RELAXED, __HIP_MEMORY_SCOPE_AGENT);
      } while (cur == g);
    }
  }
  __syncthreads();
  __builtin_amdgcn_fence(__ATOMIC_ACQUIRE, "agent");  // one buffer_inv per step
}

// ---------------- segment mean ----------------
__global__ void seg_scatter(const int* __restrict__ ids, const float* __restrict__ hidden,
                            float* __restrict__ sums, float* __restrict__ counts)
{
  int r = blockIdx.x;
  int id = ids[r];
  const float* h = hidden + (long)r * DD;
  float* s = sums + (long)id * DD;
  for (int d = threadIdx.x; d < DD; d += 256)
    atomicAdd(&s[d], h[d]);
  if (threadIdx.x == 0) atomicAdd(&counts[id], 1.0f);
}

__global__ void build_x(const int* __restrict__ ids, const float* __restrict__ hidden,
                        const float* __restrict__ sums, const float* __restrict__ counts,
                        unsigned short* __restrict__ x)
{
  int r = blockIdx.x;
  int id = ids[r];
  float inv = 1.0f / fmaxf(counts[id], 1.0f);
  const float* h = hidden + (long)r * DD;
  const float* s = sums + (long)id * DD;
  unsigned short* xr = x + (long)r * IN2;
  for (int d = threadIdx.x; d < DD; d += 256) {
    xr[d]      = f2bf(h[d]);
    xr[DD + d] = f2bf(s[d] * inv);
  }
}

// -------- weight conversion with gate-interleave permutation: row' = u*4+g <- row g*768+u --------
__global__ void conv_w_perm(const float* __restrict__ w, unsigned short* __restrict__ o, int K)
{
  long i = (long)blockIdx.x * 256 + threadIdx.x;
  if (i >= (long)G4 * K) return;
  int row = (int)(i / K); int k = (int)(i - (long)row * K);
  int u = row >> 2, g = row & 3;
  o[i] = f2bf(w[((long)(g * DD + u)) * K + k]);
}

__global__ void conv_bias_perm(const float* __restrict__ bif, const float* __restrict__ bhf,
                               const float* __restrict__ bib, const float* __restrict__ bhb,
                               float* __restrict__ o)
{
  int n = blockIdx.x * 256 + threadIdx.x;
  if (n >= NB2) return;
  int d = n / G4, rr = n - d * G4, u = rr >> 2, g = rr & 3;
  int s = g * DD + u;
  o[n] = d ? (bib[s] + bhb[s]) : (bif[s] + bhf[s]);
}

// ---------------- GEMM: C[m,n] = sum_k A[m,k]*B[n,k] + bias[n], bf16 out ----------------
__global__ __launch_bounds__(256, 2)
void gemm_bt(const unsigned short* __restrict__ A, int lda,
             const unsigned short* __restrict__ B, int ldb,
             unsigned short* __restrict__ C, int ldc,
             const float* __restrict__ bias, int K)
{
  __shared__ unsigned short lA[128 * 32];
  __shared__ unsigned short lB[128 * 32];
  const int t = threadIdx.x;
  const int lane = t & 63;
  const int wv = t >> 6;
  const int wm = wv >> 1, wn = wv & 1;
  const int l15 = lane & 15, q = lane >> 4;
  const long m0 = (long)blockIdx.y * 128;
  const long n0 = (long)blockIdx.x * 128;
  const int rowS = t >> 2;
  const int kc = (t & 3) * 8;
  const unsigned short* gA = A + (m0 + rowS) * lda + kc;
  const unsigned short* gB = B + (n0 + rowS) * ldb + kc;
  unsigned short* dA0 = lA + (wv << 9);
  unsigned short* dA1 = lA + 2048 + (wv << 9);
  unsigned short* dB0 = lB + (wv << 9);
  unsigned short* dB1 = lB + 2048 + (wv << 9);

  floatx4 acc[4][4];
  #pragma unroll
  for (int i = 0; i < 4; i++)
    #pragma unroll
    for (int j = 0; j < 4; j++)
      acc[i][j] = (floatx4){0.f, 0.f, 0.f, 0.f};

  const long a64 = (long)64 * lda;
  const long b64 = (long)64 * ldb;
  for (int kt = 0; kt < K; kt += 32) {
    gl_lds16(gA + kt,       dA0);
    gl_lds16(gA + a64 + kt, dA1);
    gl_lds16(gB + kt,       dB0);
    gl_lds16(gB + b64 + kt, dB1);
    __syncthreads();
    short8 af[4], bfr[4];
    #pragma unroll
    for (int i = 0; i < 4; i++)
      af[i] = *(const short8*)(lA + (wm * 64 + i * 16 + l15) * 32 + q * 8);
    #pragma unroll
    for (int j = 0; j < 4; j++)
      bfr[j] = *(const short8*)(lB + (wn * 64 + j * 16 + l15) * 32 + q * 8);
    #pragma unroll
    for (int i = 0; i < 4; i++)
      #pragma unroll
      for (int j = 0; j < 4; j++)
        acc[i][j] = __builtin_amdgcn_mfma_f32_16x16x32_bf16(af[i], bfr[j], acc[i][j], 0, 0, 0);
    __syncthreads();
  }

  #pragma unroll
  for (int i = 0; i < 4; i++) {
    #pragma unroll
    for (int j = 0; j < 4; j++) {
      const long mg = m0 + wm * 64 + i * 16 + q * 4;
      const long ng = n0 + wn * 64 + j * 16 + l15;
      const float bb = bias[ng];
      #pragma unroll
      for (int r = 0; r < 4; r++)
        C[(mg + r) * ldc + ng] = f2bf(acc[i][j][r] + bb);
    }
  }
}

// ---------------- persistent bidirectional LSTM recurrence ----------------
// XCD-aware mapping (xcd = bid&7). BK=128, LDS panels [p][128][32]. ALL staging
// (A=h, B=whh, xg) via async global_load_lds -- zero per-load waits. h freshness:
// producers store sc1 (L3), consumers invalidate L2 once/step in grid_bar_acq.
// Group (ld,mt) = 24 blocks is dependency-closed (writes/reads its own 128-row band).
__global__ __launch_bounds__(256, 1)
void lstm_persist(const unsigned short* __restrict__ xg, int ldxg,
                  const unsigned short* __restrict__ whh,   // [2][3072][768] permuted
                  unsigned short* __restrict__ hbuf,        // [2][ndir][512][768]
                  unsigned short* __restrict__ outc,        // [16384][1536]
                  unsigned* bar,                            // 8 groups x 16 u32
                  int dir0, int ndir)
{
  __shared__ unsigned short bufA[16384];   // 4 panels [128][32]
  __shared__ unsigned short bufB[16384];   // 4 panels [128][32]
  __shared__ unsigned short xgs[16384];    // [128 rows][128 gate-cols]

  const int bid = blockIdx.x;
  const int xcd = bid & 7;
  const int idx = bid >> 3;
  int dm, k3;
  if (ndir == 2) { dm = idx & 7; k3 = idx >> 3; }
  else           { dm = idx & 3; k3 = idx >> 2; }
  const int ld  = (ndir == 2) ? (dm & 1) : 0;
  const int dir = dir0 + ld;
  const int mt  = (ndir == 2) ? (dm >> 1) : dm;
  const int nt  = k3 * 8 + xcd;
  const int m0 = mt * 128, n0 = nt * 128;
  unsigned* gbar = bar + dm * 16;

  const int t0 = threadIdx.x;
  const int lane = t0 & 63;
  const int wv = t0 >> 6;
  const int wm = wv >> 1, wn = wv & 1;
  const int l15 = lane & 15, q = lane >> 4;
  const int baseLane = lane & ~3;
  const long ldoff = (ndir == 2 && ld == 1) ? (long)G4 : 0;

  const unsigned short* Bdir = whh + (long)dir * G4 * DD;
  // staging geometry (shared by A and B): 16 rows x 64B per wave-instr
  const int srow = lane >> 2;         // 0..15
  const int scol = (lane & 3) * 8;    // 0,8,16,24 shorts

  float c_reg[4][4][4];
  #pragma unroll
  for (int i = 0; i < 4; i++)
    #pragma unroll
    for (int j = 0; j < 4; j++)
      #pragma unroll
      for (int r = 0; r < 4; r++)
        c_reg[i][j][r] = 0.f;

  for (int s = 0; s < BB; s++) {
    const int tt = dir ? (BB - 1 - s) : s;
    const unsigned short* hRead = hbuf + (((long)(s & 1)) * ndir + ld) * ((long)SS * DD);
    unsigned short* hw = hbuf + (((long)((s + 1) & 1)) * ndir + ld) * ((long)SS * DD);

    // stage xg tile [128 rows][128 cols] -> LDS (async direct-to-LDS)
    {
      const unsigned short* xrow = xg + ((long)tt * SS + m0) * ldxg + ldoff + n0;
      #pragma unroll
      for (int c = 0; c < 8; c++) {
        int row = c * 16 + (t0 >> 4);
        gl_lds16(xrow + (long)row * ldxg + (t0 & 15) * 8,
                 xgs + c * 2048 + wv * 512 + lane * 8);
      }
    }

    floatx4 acc[4][4];
    #pragma unroll
    for (int i = 0; i < 4; i++)
      #pragma unroll
      for (int j = 0; j < 4; j++)
        acc[i][j] = (floatx4){0.f, 0.f, 0.f, 0.f};

    for (int kt = 0; kt < 6; kt++) {
      const int kb = kt << 7;
      #pragma unroll
      for (int p = 0; p < 4; p++)
        #pragma unroll
        for (int rbh = 0; rbh < 2; rbh++) {
          int rb = (wv * 2 + rbh) * 16 + srow;
          // B (whh, read-only, L2-resident)
          gl_lds16(Bdir + (long)(n0 + rb) * DD + kb + p * 32 + scol,
                   bufB + p * 4096 + (wv * 2 + rbh) * 512 + lane * 8);
          // A (h, fresh via step-start L2 invalidation; producers wrote sc1 to L3)
          gl_lds16(hRead + (long)(m0 + rb) * DD + kb + p * 32 + scol,
                   bufA + p * 4096 + (wv * 2 + rbh) * 512 + lane * 8);
        }
      __syncthreads();
      #pragma unroll
      for (int ks = 0; ks < 4; ks++) {
        short8 af[4], bfr[4];
        #pragma unroll
        for (int i = 0; i < 4; i++)
          af[i] = *(const short8*)(bufA + ks * 4096 + (wm * 64 + i * 16 + l15) * 32 + q * 8);
        #pragma unroll
        for (int j = 0; j < 4; j++)
          bfr[j] = *(const short8*)(bufB + ks * 4096 + (wn * 64 + j * 16 + l15) * 32 + q * 8);
        #pragma unroll
        for (int i = 0; i < 4; i++)
          #pragma unroll
          for (int j = 0; j < 4; j++)
            acc[i][j] = __builtin_amdgcn_mfma_f32_16x16x32_bf16(af[i], bfr[j], acc[i][j], 0, 0, 0);
      }
      __syncthreads();
    }

    // fused gate epilogue (xg from LDS)
    #pragma unroll
    for (int i = 0; i < 4; i++) {
      #pragma unroll
      for (int j = 0; j < 4; j++) {
        const int mgl = wm * 64 + i * 16 + q * 4;
        const int ngl = wn * 64 + j * 16 + l15;
        const int u  = (n0 + ngl) >> 2;
        #pragma unroll
        for (int r = 0; r < 4; r++) {
          float v = acc[i][j][r] + bf2f(xgs[(mgl + r) * 128 + ngl]);
          float gi = __shfl(v, baseLane + 0, 64);
          float gf = __shfl(v, baseLane + 1, 64);
          float gg = __shfl(v, baseLane + 2, 64);
          float go = __shfl(v, baseLane + 3, 64);
          float c = sigf(gf) * c_reg[i][j][r] + sigf(gi) * tanhfast(gg);
          float h = sigf(go) * tanhfast(c);
          c_reg[i][j][r] = c;
          if ((l15 & 3) == 0) {
            unsigned short hb = f2bf(h);
            __hip_atomic_store(&hw[((long)(m0 + mgl + r)) * DD + u], hb,
                               __ATOMIC_RELAXED, __HIP_MEMORY_SCOPE_AGENT);
            outc[((long)(tt * SS + m0 + mgl + r)) * IN2 + dir * DD + u] = hb;
          }
        }
      }
    }
    if (s < BB - 1) grid_bar_acq(gbar, 24);
  }
}

// ---------------- final linear [16384,1536](bf16) x [9,1536]^T ----------------
__global__ void final_linear(const unsigned short* __restrict__ xin, const float* __restrict__ w,
                             const float* __restrict__ b, float* __restrict__ out)
{
  __shared__ float red[NCLS * 256];
  int row = blockIdx.x;
  const unsigned short* x = xin + (long)row * IN2;
  float p[NCLS];
  #pragma unroll
  for (int c = 0; c < NCLS; c++) p[c] = 0.f;
  for (int k = threadIdx.x; k < IN2; k += 256) {
    float xv = bf2f(x[k]);
    #pragma unroll
    for (int c = 0; c < NCLS; c++) p[c] += xv * w[c * IN2 + k];
  }
  #pragma unroll
  for (int c = 0; c < NCLS; c++) red[c * 256 + threadIdx.x] = p[c];
  __syncthreads();
  for (int s = 128; s > 0; s >>= 1) {
    if (threadIdx.x < s) {
      #pragma unroll
      for (int c = 0; c < NCLS; c++)
        red[c * 256 + threadIdx.x] += red[c * 256 + threadIdx.x + s];
    }
    __syncthreads();
  }
  if (threadIdx.x < NCLS)
    out[(long)row * NCLS + threadIdx.x] = red[threadIdx.x * 256] + b[threadIdx.x];
}

extern "C" void kernel_launch(void* const* d_in, const int* in_sizes, int n_in,
                              void* d_out, int out_size, void* d_ws, size_t ws_size,
                              hipStream_t stream)
{
  const int*   batch  = (const int*)d_in[0];
  const float* hidden = (const float*)d_in[1];
  const float* w_ih_f = (const float*)d_in[2];
  const float* w_hh_f = (const float*)d_in[3];
  const float* b_ih_f = (const float*)d_in[4];
  const float* b_hh_f = (const float*)d_in[5];
  const float* w_ih_b = (const float*)d_in[6];
  const float* w_hh_b = (const float*)d_in[7];
  const float* b_ih_b = (const float*)d_in[8];
  const float* b_hh_b = (const float*)d_in[9];
  const float* lin_w  = (const float*)d_in[10];
  const float* lin_b  = (const float*)d_in[11];
  float* out = (float*)d_out;

  char* ws = (char*)d_ws;
  size_t off = 0;
  auto alloc = [&](size_t bytes) -> char* {
    char* p = ws + off;
    off += (bytes + 255) & ~(size_t)255;
    return p;
  };

  const size_t SZ_XG_A = (size_t)ROWS * NB2 * 2;      // 201.3 MB
  const size_t SZ_XG_B = (size_t)ROWS * G4  * 2;      // 100.7 MB
  const size_t SZ_XBF  = (size_t)ROWS * IN2 * 2;      //  50.3 MB
  const size_t SZ_W    = (size_t)G4 * IN2 * 2;        //   9.4 MB
  const size_t SZ_BIAS = (size_t)NB2 * 4;
  const size_t SZ_HBUF = (size_t)2 * 2 * SS * DD * 2; //   3.1 MB
  const size_t SZ_BAR  = 512;
  const size_t SZ_SUMS = (size_t)VOCAB * DD * 4 + (size_t)VOCAB * 4;

  const size_t NEED_C = SZ_XG_A + SZ_XBF + SZ_W + SZ_BIAS + SZ_HBUF + SZ_BAR + 8 * 256;
  const bool combined = ws_size >= NEED_C;

  const long nWIH = (long)G4 * IN2;
  const long nWHH = (long)G4 * DD;

  if (combined) {
    unsigned short* xg   = (unsigned short*)alloc(SZ_XG_A);
    unsigned short* xbf  = (unsigned short*)alloc(SZ_XBF);   // x input, later reused as outc
    unsigned short* wbuf = (unsigned short*)alloc(SZ_W);     // wih_f -> wih_b -> whh(both)
    float*          bias = (float*)alloc(SZ_BIAS);
    unsigned short* hbuf = (unsigned short*)alloc(SZ_HBUF);
    unsigned*       bar  = (unsigned*)alloc(SZ_BAR);
    float* sums   = (float*)xg;                              // overlay, consumed pre-xg-GEMM
    float* counts = sums + (size_t)VOCAB * DD;

    hipMemsetAsync(sums, 0, SZ_SUMS, stream);
    hipMemsetAsync(bar, 0, SZ_BAR, stream);
    seg_scatter<<<ROWS, 256, 0, stream>>>(batch, hidden, sums, counts);
    build_x<<<ROWS, 256, 0, stream>>>(batch, hidden, sums, counts, xbf);
    conv_bias_perm<<<(NB2 + 255) / 256, 256, 0, stream>>>(b_ih_f, b_hh_f, b_ih_b, b_hh_b, bias);

    for (int dir = 0; dir < 2; dir++) {
      conv_w_perm<<<(unsigned)((nWIH + 255) / 256), 256, 0, stream>>>(dir ? w_ih_b : w_ih_f, wbuf, IN2);
      dim3 grid(G4 / 128, ROWS / 128, 1);
      gemm_bt<<<grid, 256, 0, stream>>>(xbf, IN2, wbuf, IN2,
                                        xg + (size_t)dir * G4, NB2,
                                        bias + (size_t)dir * G4, IN2);
    }
    conv_w_perm<<<(unsigned)((nWHH + 255) / 256), 256, 0, stream>>>(w_hh_f, wbuf, DD);
    conv_w_perm<<<(unsigned)((nWHH + 255) / 256), 256, 0, stream>>>(w_hh_b, wbuf + (size_t)G4 * DD, DD);

    hipMemsetAsync(hbuf, 0, SZ_HBUF, stream);
    lstm_persist<<<192, 256, 0, stream>>>(xg, NB2, wbuf, hbuf, xbf, bar, 0, 2);
    final_linear<<<ROWS, 256, 0, stream>>>(xbf, lin_w, lin_b, out);
  } else {
    // direction-sequential (~223 MB, proven to fit)
    unsigned short* xg   = (unsigned short*)alloc(SZ_XG_B);
    unsigned short* xbf  = (unsigned short*)alloc(SZ_XBF);
    unsigned short* outc = (unsigned short*)alloc(SZ_XBF);
    unsigned short* wih  = (unsigned short*)alloc(SZ_W);
    unsigned short* whh  = (unsigned short*)alloc(SZ_W);
    float*          bias = (float*)alloc(SZ_BIAS);
    unsigned short* hbuf = (unsigned short*)alloc(SZ_HBUF);
    unsigned*       bar  = (unsigned*)alloc(SZ_BAR);
    float* sums   = (float*)xg;
    float* counts = sums + (size_t)VOCAB * DD;

    hipMemsetAsync(sums, 0, SZ_SUMS, stream);
    hipMemsetAsync(bar, 0, SZ_BAR, stream);
    seg_scatter<<<ROWS, 256, 0, stream>>>(batch, hidden, sums, counts);
    build_x<<<ROWS, 256, 0, stream>>>(batch, hidden, sums, counts, xbf);
    conv_bias_perm<<<(NB2 + 255) / 256, 256, 0, stream>>>(b_ih_f, b_hh_f, b_ih_b, b_hh_b, bias);
    conv_w_perm<<<(unsigned)((nWHH + 255) / 256), 256, 0, stream>>>(w_hh_f, whh, DD);
    conv_w_perm<<<(unsigned)((nWHH + 255) / 256), 256, 0, stream>>>(w_hh_b, whh + (size_t)G4 * DD, DD);

    for (int dir = 0; dir < 2; dir++) {
      conv_w_perm<<<(unsigned)((nWIH + 255) / 256), 256, 0, stream>>>(dir ? w_ih_b : w_ih_f, wih, IN2);
      {
        dim3 grid(G4 / 128, ROWS / 128, 1);
        gemm_bt<<<grid, 256, 0, stream>>>(xbf, IN2, wih, IN2, xg, G4,
                                          bias + (size_t)dir * G4, IN2);
      }
      hipMemsetAsync(hbuf, 0, SZ_HBUF, stream);
      lstm_persist<<<96, 256, 0, stream>>>(xg, G4, whh, hbuf, outc, bar, dir, 1);
    }
    final_linear<<<ROWS, 256, 0, stream>>>(outc, lin_w, lin_b, out);
  }
}